// Round 6
// baseline (121.642 us; speedup 1.0000x reference)
//
#include <hip/hip_runtime.h>
#include <stdint.h>

#define IN_F     4096
#define OUT_F    4096
#define BATCH    128
#define NNZ      1600000
#define NSEG2    400       // scatter blocks; block s owns entries [s*4000, +4000)
#define CHUNK2   4000      // NNZ / NSEG2 exactly (1000 int4 quads)
#define NBKT     512       // row buckets of 8 rows (OUT_F/8)
#define BCAP     4096      // per-bucket entry capacity (mean 3125, +17 sigma)
#define NGRAN    (IN_F / 8)  // 512 k-granules of 8 bf16
#define LPAD     4100      // lrow stride: 4100%32=4 -> 8 rows hit 8 distinct banks

typedef float f32x4_t __attribute__((ext_vector_type(4)));
typedef short s16x8_t __attribute__((ext_vector_type(8)));

// fp32 -> bf16 bits (RNE)
__device__ __forceinline__ unsigned f2bf(float f) {
  unsigned u = __float_as_uint(f);
  return (u + 0x7fffu + ((u >> 16) & 1u)) >> 16;
}

// ---------- K1: bucket-scatter (replaces counting sort) + fused B convert ----------
// Blocks [0,NSEG2): histogram 512 buckets in LDS, reserve contiguous slabs in the
// per-bucket global arrays via ONE atomicAdd per (block,bucket), scatter entries
// packed as val16|col12|row3. Blocks [NSEG2, +32): inp -> granule-major bf16 bg.
__global__ __launch_bounds__(512) void k_bucket(const float* __restrict__ vals,
                                                const int* __restrict__ rows,
                                                const int* __restrict__ cols,
                                                const float* __restrict__ inp,
                                                unsigned* __restrict__ gcnt,
                                                unsigned* __restrict__ gbuf,
                                                uint4* __restrict__ bg) {
  __shared__ unsigned hist[NBKT];
  const int t = threadIdx.x;
  const int s = blockIdx.x;

  if (s >= NSEG2) {                                 // ---- prep branch ----
    const int bp  = s - NSEG2;                      // 0..31
    const int row = bp * 4 + (t >> 7);              // 0..127
    const int tt  = t & 127;
    const float4* __restrict__ src = (const float4*)(inp + (size_t)row * IN_F);
    #pragma unroll
    for (int j = 0; j < 4; ++j) {
      const int g = 4 * tt + j;                     // 0..511
      const float4 a = src[2 * g];
      const float4 b = src[2 * g + 1];
      uint4 o;
      o.x = f2bf(a.x) | (f2bf(a.y) << 16);
      o.y = f2bf(a.z) | (f2bf(a.w) << 16);
      o.z = f2bf(b.x) | (f2bf(b.y) << 16);
      o.w = f2bf(b.z) | (f2bf(b.w) << 16);
      bg[(size_t)g * BATCH + row] = o;
    }
    return;
  }

  hist[t] = 0u;
  __syncthreads();

  const size_t qb = (size_t)s * (CHUNK2 / 4);
  const int4   ra = ((const int4*)rows)[qb + t];
  const int4   ca = ((const int4*)cols)[qb + t];
  const float4 va = ((const float4*)vals)[qb + t];
  const bool hasB = (t + 512) < (CHUNK2 / 4);       // t < 488
  int4 rb = make_int4(0, 0, 0, 0), cb = rb;
  float4 vb = make_float4(0.f, 0.f, 0.f, 0.f);
  if (hasB) {
    rb = ((const int4*)rows)[qb + 512 + t];
    cb = ((const int4*)cols)[qb + 512 + t];
    vb = ((const float4*)vals)[qb + 512 + t];
  }

  atomicAdd(&hist[(unsigned)ra.x >> 3], 1u); atomicAdd(&hist[(unsigned)ra.y >> 3], 1u);
  atomicAdd(&hist[(unsigned)ra.z >> 3], 1u); atomicAdd(&hist[(unsigned)ra.w >> 3], 1u);
  if (hasB) {
    atomicAdd(&hist[(unsigned)rb.x >> 3], 1u); atomicAdd(&hist[(unsigned)rb.y >> 3], 1u);
    atomicAdd(&hist[(unsigned)rb.z >> 3], 1u); atomicAdd(&hist[(unsigned)rb.w >> 3], 1u);
  }
  __syncthreads();

  // reserve a contiguous slab per bucket; hist[b] becomes the running global cursor
  const unsigned base = atomicAdd(&gcnt[t], hist[t]);
  hist[t] = base;
  __syncthreads();

  #define SCAT(R, C, V) {                                              \
    const unsigned bb = (unsigned)(R) >> 3;                            \
    const unsigned p  = atomicAdd(&hist[bb], 1u);                      \
    if (p < (unsigned)BCAP)                                            \
      gbuf[(size_t)bb * BCAP + p] =                                    \
          (f2bf(V) << 16) | ((unsigned)(C) << 3) | ((unsigned)(R) & 7u); }
  SCAT(ra.x, ca.x, va.x) SCAT(ra.y, ca.y, va.y)
  SCAT(ra.z, ca.z, va.z) SCAT(ra.w, ca.w, va.w)
  if (hasB) {
    SCAT(rb.x, cb.x, vb.x) SCAT(rb.y, cb.y, vb.y)
    SCAT(rb.z, cb.z, vb.z) SCAT(rb.w, cb.w, vb.w)
  }
  #undef SCAT
}

// ---------- K2: densify bucket -> granule-major bf16 W: wg[g][row] ----------
// Block owns bucket b = 8 rows in 8x4100 fp32 LDS (bank-padded). Entry stream is
// CONTIGUOUS and coalesced; row recovered from entry low bits.
__global__ __launch_bounds__(256) void k_dense2(const unsigned* __restrict__ gbuf,
                                                const unsigned* __restrict__ gcnt,
                                                uint4* __restrict__ wg) {
  __shared__ float lrow[8][LPAD];                   // 131.2 KB
  const int t   = threadIdx.x;
  const int bkt = blockIdx.x;

  for (int i = t; i < (8 * LPAD) / 4; i += 256)
    ((float4*)lrow)[i] = make_float4(0.f, 0.f, 0.f, 0.f);
  unsigned n = gcnt[bkt];
  if (n > (unsigned)BCAP) n = BCAP;
  __syncthreads();

  const unsigned* __restrict__ src = gbuf + (size_t)bkt * BCAP;
  for (unsigned i = t; i < n; i += 256) {
    const unsigned e = src[i];
    atomicAdd(&lrow[e & 7u][(e >> 3) & 0xfffu], __uint_as_float(e & 0xffff0000u));
  }
  __syncthreads();

  const int r0 = bkt * 8;
  #pragma unroll
  for (int j = 0; j < 16; ++j) {
    const int idx  = j * 256 + t;                   // 0..4095 = 512 g * 8 rows
    const int rowl = idx & 7;
    const int g    = idx >> 3;
    const float* p = &lrow[rowl][g * 8];
    uint4 o;
    o.x = f2bf(p[0]) | (f2bf(p[1]) << 16);
    o.y = f2bf(p[2]) | (f2bf(p[3]) << 16);
    o.z = f2bf(p[4]) | (f2bf(p[5]) << 16);
    o.w = f2bf(p[6]) | (f2bf(p[7]) << 16);
    wg[(size_t)g * OUT_F + r0 + rowl] = o;
  }
}

// ---------- K3: full-K GEMM -> out directly (verified round 5, verbatim) ----------
__global__ __launch_bounds__(512) void k_gemm4(const uint4* __restrict__ wg,
                                               const uint4* __restrict__ bg,
                                               const float* __restrict__ bias,
                                               float* __restrict__ out) {
  __shared__ float red[8][BATCH][20];               // 80 KB
  const int t    = threadIdx.x;
  const int lane = t & 63;
  const int wid  = t >> 6;                          // 0..7 = K chunk
  const int bx   = blockIdx.x;                      // 0..255
  const int l15  = lane & 15;
  const int lk   = lane >> 4;                       // 0..3
  const int rt   = bx * 16;

  f32x4_t acc[8];
  #pragma unroll
  for (int i = 0; i < 8; ++i) { acc[i][0] = 0.f; acc[i][1] = 0.f; acc[i][2] = 0.f; acc[i][3] = 0.f; }

  const int g0 = wid * 64 + lk;
  for (int s = 0; s < 16; ++s) {
    const int g = g0 + s * 4;
    const s16x8_t av = *(const s16x8_t*)&wg[(size_t)g * OUT_F + rt + l15];
    #pragma unroll
    for (int nf = 0; nf < 8; ++nf) {
      const s16x8_t bv = *(const s16x8_t*)&bg[(size_t)g * BATCH + nf * 16 + l15];
      acc[nf] = __builtin_amdgcn_mfma_f32_16x16x32_bf16(av, bv, acc[nf], 0, 0, 0);
    }
  }

  #pragma unroll
  for (int nf = 0; nf < 8; ++nf)
    *(f32x4_t*)&red[wid][nf * 16 + l15][lk * 4] = acc[nf];
  __syncthreads();

  const int b   = t >> 2;                           // 0..127
  const int rr0 = (t & 3) * 4;                      // 0,4,8,12
  float4 sum = *(const float4*)&bias[rt + rr0];
  #pragma unroll
  for (int w = 0; w < 8; ++w) {
    const float4 p = *(const float4*)&red[w][b][rr0];
    sum.x += p.x; sum.y += p.y; sum.z += p.z; sum.w += p.w;
  }
  *(float4*)&out[(size_t)b * OUT_F + rt + rr0] = sum;
}

// ---------- fallback (tiny workspace): correct but slow ----------
__global__ __launch_bounds__(256) void k_init_out(const float* __restrict__ bias,
                                                  float* __restrict__ out) {
  const int i = blockIdx.x * 256 + threadIdx.x;
  out[i] = bias[i & (OUT_F - 1)];
}
__global__ __launch_bounds__(256) void k_atomic(const float* __restrict__ vals,
                                                const int* __restrict__ rows,
                                                const int* __restrict__ cols,
                                                const float* __restrict__ inp,
                                                float* __restrict__ out) {
  const int i = blockIdx.x * 256 + threadIdx.x;
  if (i >= NNZ) return;
  const float v = vals[i];
  const int   r = rows[i];
  const int   c = cols[i];
  for (int b = 0; b < BATCH; ++b)
    atomicAdd(&out[(size_t)b * OUT_F + r], v * inp[(size_t)b * IN_F + c]);
}

extern "C" void kernel_launch(void* const* d_in, const int* in_sizes, int n_in,
                              void* d_out, int out_size, void* d_ws, size_t ws_size,
                              hipStream_t stream) {
  const float* inp      = (const float*)d_in[0];
  const float* w_values = (const float*)d_in[1];
  const int*   w_rows   = (const int*)d_in[2];
  const int*   w_cols   = (const int*)d_in[3];
  const float* bias     = (const float*)d_in[4];
  float*       out      = (float*)d_out;

  const size_t w_bytes   = (size_t)NGRAN * OUT_F * 16;      // 32 MB granule-major W
  const size_t ibf_bytes = (size_t)NGRAN * BATCH * 16;      // 1 MB granule-major B
  const size_t gbuf_bytes= (size_t)NBKT * BCAP * 4;         // 8 MB bucketed entries
  const size_t gcnt_bytes= (size_t)NBKT * 4;                // 2 KB cursors
  const size_t need = w_bytes + ibf_bytes + gbuf_bytes + gcnt_bytes + 64;

  if (ws_size >= need) {
    char* ws = (char*)d_ws;
    uint4*    wg   = (uint4*)ws;     ws += w_bytes;
    uint4*    bg   = (uint4*)ws;     ws += ibf_bytes;
    unsigned* gbuf = (unsigned*)ws;  ws += gbuf_bytes;
    unsigned* gcnt = (unsigned*)ws;

    hipMemsetAsync(gcnt, 0, gcnt_bytes, stream);
    k_bucket<<<NSEG2 + 32, 512, 0, stream>>>(w_values, w_rows, w_cols, inp,
                                             gcnt, gbuf, bg);
    k_dense2<<<NBKT, 256, 0, stream>>>(gbuf, gcnt, wg);
    k_gemm4<<<OUT_F / 16, 512, 0, stream>>>(wg, bg, bias, out);
  } else {
    k_init_out<<<(BATCH * OUT_F) / 256, 256, 0, stream>>>(bias, out);
    k_atomic<<<(NNZ + 255) / 256, 256, 0, stream>>>(w_values, w_rows, w_cols, inp, out);
  }
}

// Round 7
// 111.715 us; speedup vs baseline: 1.0889x; 1.0889x over previous
//
#include <hip/hip_runtime.h>
#include <stdint.h>

#define IN_F     4096
#define OUT_F    4096
#define BATCH    128
#define NNZ      1600000
#define NSEG2    400       // scatter blocks; block s owns entries [s*4000, +4000)
#define CHUNK2   4000      // NNZ / NSEG2 exactly (1000 int4 quads)
#define NBKT     256       // row buckets of 16 rows (OUT_F/16)
#define BCAP     8192      // per-bucket entry capacity (mean 6250, +24 sigma)
#define NGRAN    (IN_F / 8)  // 512 k-granules of 8 bf16

typedef float f32x4_t __attribute__((ext_vector_type(4)));
typedef short s16x8_t __attribute__((ext_vector_type(8)));

// fp32 -> bf16 bits (RNE)
__device__ __forceinline__ unsigned f2bf(float f) {
  unsigned u = __float_as_uint(f);
  return (u + 0x7fffu + ((u >> 16) & 1u)) >> 16;
}

// ---------- K1: bucket-scatter (16-row buckets) + fused B convert ----------
// Blocks [0,NSEG2): LDS histogram of 256 buckets, ONE global atomicAdd per
// (block,bucket) to reserve a contiguous slab, then scatter entries packed as
// val16|col12|row4 (exactly 32 bits). Blocks [NSEG2,+32): inp -> bg[g][row] bf16.
__global__ __launch_bounds__(512) void k_bucket16(const float* __restrict__ vals,
                                                  const int* __restrict__ rows,
                                                  const int* __restrict__ cols,
                                                  const float* __restrict__ inp,
                                                  unsigned* __restrict__ gcnt,
                                                  unsigned* __restrict__ gbuf,
                                                  uint4* __restrict__ bg) {
  __shared__ unsigned hist[NBKT];
  const int t = threadIdx.x;
  const int s = blockIdx.x;

  if (s >= NSEG2) {                                 // ---- prep branch ----
    const int bp  = s - NSEG2;                      // 0..31
    const int row = bp * 4 + (t >> 7);              // 0..127
    const int tt  = t & 127;
    const float4* __restrict__ src = (const float4*)(inp + (size_t)row * IN_F);
    #pragma unroll
    for (int j = 0; j < 4; ++j) {
      const int g = 4 * tt + j;                     // 0..511
      const float4 a = src[2 * g];
      const float4 b = src[2 * g + 1];
      uint4 o;
      o.x = f2bf(a.x) | (f2bf(a.y) << 16);
      o.y = f2bf(a.z) | (f2bf(a.w) << 16);
      o.z = f2bf(b.x) | (f2bf(b.y) << 16);
      o.w = f2bf(b.z) | (f2bf(b.w) << 16);
      bg[(size_t)g * BATCH + row] = o;
    }
    return;
  }

  if (t < NBKT) hist[t] = 0u;
  __syncthreads();

  const size_t qb = (size_t)s * (CHUNK2 / 4);
  const int4   ra = ((const int4*)rows)[qb + t];
  const int4   ca = ((const int4*)cols)[qb + t];
  const float4 va = ((const float4*)vals)[qb + t];
  const bool hasB = (t + 512) < (CHUNK2 / 4);       // t < 488
  int4 rb = make_int4(0, 0, 0, 0), cb = rb;
  float4 vb = make_float4(0.f, 0.f, 0.f, 0.f);
  if (hasB) {
    rb = ((const int4*)rows)[qb + 512 + t];
    cb = ((const int4*)cols)[qb + 512 + t];
    vb = ((const float4*)vals)[qb + 512 + t];
  }

  atomicAdd(&hist[(unsigned)ra.x >> 4], 1u); atomicAdd(&hist[(unsigned)ra.y >> 4], 1u);
  atomicAdd(&hist[(unsigned)ra.z >> 4], 1u); atomicAdd(&hist[(unsigned)ra.w >> 4], 1u);
  if (hasB) {
    atomicAdd(&hist[(unsigned)rb.x >> 4], 1u); atomicAdd(&hist[(unsigned)rb.y >> 4], 1u);
    atomicAdd(&hist[(unsigned)rb.z >> 4], 1u); atomicAdd(&hist[(unsigned)rb.w >> 4], 1u);
  }
  __syncthreads();

  if (t < NBKT) {
    const unsigned base = atomicAdd(&gcnt[t], hist[t]);
    hist[t] = base;
  }
  __syncthreads();

  #define SCAT(R, C, V) {                                              \
    const unsigned bb = (unsigned)(R) >> 4;                            \
    const unsigned p  = atomicAdd(&hist[bb], 1u);                      \
    if (p < (unsigned)BCAP)                                            \
      gbuf[(size_t)bb * BCAP + p] =                                    \
          (f2bf(V) << 16) | ((unsigned)(C) << 4) | ((unsigned)(R) & 15u); }
  SCAT(ra.x, ca.x, va.x) SCAT(ra.y, ca.y, va.y)
  SCAT(ra.z, ca.z, va.z) SCAT(ra.w, ca.w, va.w)
  if (hasB) {
    SCAT(rb.x, cb.x, vb.x) SCAT(rb.y, cb.y, vb.y)
    SCAT(rb.z, cb.z, vb.z) SCAT(rb.w, cb.w, vb.w)
  }
  #undef SCAT
}

// ---------- K2: FUSED densify(LDS bf16 image) + GEMM -> out ----------
// Block bx owns bucket bx = W rows [16bx,+16). Phase A: ds_pk_add_bf16 entries
// into a 128KB LDS image laid out as MFMA A-fragments: img[(g*16+row)*8 + el].
// Phase B: verbatim gemm4 MFMA math with A read from LDS; red[] aliases the
// image (dead after MFMAs). No global W ever materialized.
__global__ __launch_bounds__(512) void k_fuse(const unsigned* __restrict__ gbuf,
                                              const unsigned* __restrict__ gcnt,
                                              const uint4* __restrict__ bg,
                                              const float* __restrict__ bias,
                                              float* __restrict__ out) {
  __shared__ __align__(16) char smem[131072];       // 128 KB: image, then red alias
  unsigned short* __restrict__ img = (unsigned short*)smem;
  const int t   = threadIdx.x;
  const int bkt = blockIdx.x;                       // 0..255
  const int rt  = bkt * 16;

  {
    uint4* img4 = (uint4*)smem;
    const uint4 z = make_uint4(0u, 0u, 0u, 0u);
    #pragma unroll
    for (int j = 0; j < 16; ++j) img4[j * 512 + t] = z;
  }
  unsigned n = gcnt[bkt];
  if (n > (unsigned)BCAP) n = BCAP;
  __syncthreads();

  const unsigned* __restrict__ src = gbuf + (size_t)bkt * BCAP;
  for (unsigned i = t; i < n; i += 512) {
    const unsigned e = src[i];
    const unsigned c = (e >> 4) & 0xfffu;
    const unsigned r = e & 15u;
    const unsigned v = e >> 16;                     // bf16 bits
    // byte offset of the 4B pair holding element (c&7) of (granule c>>3, row r)
    const unsigned byte = (c >> 3) * 256u + r * 16u + ((c & 7u) >> 1) * 4u;
    const unsigned data = (c & 1u) ? (v << 16) : v;
    const unsigned addr = (unsigned)(uintptr_t)&smem[byte];
    asm volatile("ds_pk_add_bf16 %0, %1" :: "v"(addr), "v"(data) : "memory");
  }
  __syncthreads();

  // ---- Phase B: GEMM for these 16 rows (fragment math verbatim from k_gemm4) ----
  const int lane = t & 63;
  const int wid  = t >> 6;                          // 0..7 = K chunk
  const int l15  = lane & 15;
  const int lk   = lane >> 4;                       // 0..3

  f32x4_t acc[8];
  #pragma unroll
  for (int i = 0; i < 8; ++i) { acc[i][0] = 0.f; acc[i][1] = 0.f; acc[i][2] = 0.f; acc[i][3] = 0.f; }

  const int g0 = wid * 64 + lk;
  for (int s = 0; s < 16; ++s) {
    const int g = g0 + s * 4;
    const s16x8_t av = *(const s16x8_t*)&img[((size_t)g * 16 + l15) * 8];
    #pragma unroll
    for (int nf = 0; nf < 8; ++nf) {
      const s16x8_t bv = *(const s16x8_t*)&bg[(size_t)g * BATCH + nf * 16 + l15];
      acc[nf] = __builtin_amdgcn_mfma_f32_16x16x32_bf16(av, bv, acc[nf], 0, 0, 0);
    }
  }
  __syncthreads();                                  // image dead; safe to alias red

  float (*red)[BATCH][20] = (float (*)[BATCH][20])smem;   // 80 KB
  #pragma unroll
  for (int nf = 0; nf < 8; ++nf)
    *(f32x4_t*)&red[wid][nf * 16 + l15][lk * 4] = acc[nf];
  __syncthreads();

  const int b   = t >> 2;                           // 0..127
  const int rr0 = (t & 3) * 4;                      // 0,4,8,12
  float4 sum = *(const float4*)&bias[rt + rr0];
  #pragma unroll
  for (int w = 0; w < 8; ++w) {
    const float4 p = *(const float4*)&red[w][b][rr0];
    sum.x += p.x; sum.y += p.y; sum.z += p.z; sum.w += p.w;
  }
  *(float4*)&out[(size_t)b * OUT_F + rt + rr0] = sum;
}

// ---------- fallback (tiny workspace): correct but slow ----------
__global__ __launch_bounds__(256) void k_init_out(const float* __restrict__ bias,
                                                  float* __restrict__ out) {
  const int i = blockIdx.x * 256 + threadIdx.x;
  out[i] = bias[i & (OUT_F - 1)];
}
__global__ __launch_bounds__(256) void k_atomic(const float* __restrict__ vals,
                                                const int* __restrict__ rows,
                                                const int* __restrict__ cols,
                                                const float* __restrict__ inp,
                                                float* __restrict__ out) {
  const int i = blockIdx.x * 256 + threadIdx.x;
  if (i >= NNZ) return;
  const float v = vals[i];
  const int   r = rows[i];
  const int   c = cols[i];
  for (int b = 0; b < BATCH; ++b)
    atomicAdd(&out[(size_t)b * OUT_F + r], v * inp[(size_t)b * IN_F + c]);
}

extern "C" void kernel_launch(void* const* d_in, const int* in_sizes, int n_in,
                              void* d_out, int out_size, void* d_ws, size_t ws_size,
                              hipStream_t stream) {
  const float* inp      = (const float*)d_in[0];
  const float* w_values = (const float*)d_in[1];
  const int*   w_rows   = (const int*)d_in[2];
  const int*   w_cols   = (const int*)d_in[3];
  const float* bias     = (const float*)d_in[4];
  float*       out      = (float*)d_out;

  const size_t ibf_bytes = (size_t)NGRAN * BATCH * 16;      // 1 MB granule-major B
  const size_t gbuf_bytes= (size_t)NBKT * BCAP * 4;         // 8 MB bucketed entries
  const size_t gcnt_bytes= (size_t)NBKT * 4;                // 1 KB cursors
  const size_t need = ibf_bytes + gbuf_bytes + gcnt_bytes + 64;

  if (ws_size >= need) {
    char* ws = (char*)d_ws;
    uint4*    bg   = (uint4*)ws;     ws += ibf_bytes;
    unsigned* gbuf = (unsigned*)ws;  ws += gbuf_bytes;
    unsigned* gcnt = (unsigned*)ws;

    hipMemsetAsync(gcnt, 0, gcnt_bytes, stream);
    k_bucket16<<<NSEG2 + 32, 512, 0, stream>>>(w_values, w_rows, w_cols, inp,
                                               gcnt, gbuf, bg);
    k_fuse<<<NBKT, 512, 0, stream>>>(gbuf, gcnt, bg, bias, out);
  } else {
    k_init_out<<<(BATCH * OUT_F) / 256, 256, 0, stream>>>(bias, out);
    k_atomic<<<(NNZ + 255) / 256, 256, 0, stream>>>(w_values, w_rows, w_cols, inp, out);
  }
}

// Round 9
// 108.977 us; speedup vs baseline: 1.1162x; 1.0251x over previous
//
#include <hip/hip_runtime.h>
#include <stdint.h>

#define IN_F     4096
#define OUT_F    4096
#define BATCH    128
#define NNZ      1600000
#define NSEG2    400       // scatter blocks; block s owns entries [s*4000, +4000)
#define CHUNK2   4000      // NNZ / NSEG2 exactly (1000 int4 quads)
#define NBKT     256       // row buckets of 16 rows (OUT_F/16)
#define BCAP     8192      // per-bucket entry capacity (mean 6250, +25 sigma)
#define NGRAN    (IN_F / 8)  // 512 k-granules of 8 bf16

typedef float f32x4_t __attribute__((ext_vector_type(4)));
typedef short s16x8_t __attribute__((ext_vector_type(8)));

// fp32 -> bf16 bits (RNE)
__device__ __forceinline__ unsigned f2bf(float f) {
  unsigned u = __float_as_uint(f);
  return (u + 0x7fffu + ((u >> 16) & 1u)) >> 16;
}

// ---------- K1: bucket kernel with in-LDS 256-bin counting sort ----------
// Blocks [0,NSEG2): hist -> 1-wave scan -> LDS scatter (sorted by bucket) ->
// COALESCED flush of per-bucket runs into globally-reserved slabs (one
// atomicAdd per (block,bucket)). Entries packed val16|col12|row4.
// Blocks [NSEG2,+32): inp -> granule-major bf16 bg[g][row].
__global__ __launch_bounds__(512) void k_bucket16(const float* __restrict__ vals,
                                                  const int* __restrict__ rows,
                                                  const int* __restrict__ cols,
                                                  const float* __restrict__ inp,
                                                  unsigned* __restrict__ gcnt,
                                                  unsigned* __restrict__ gbuf,
                                                  uint4* __restrict__ bg) {
  __shared__ unsigned hist[NBKT];                   // counts
  __shared__ unsigned lcur[NBKT];                   // local scatter cursors
  __shared__ unsigned lorig[NBKT];                  // local exclusive bases
  __shared__ unsigned gbase[NBKT];                  // global slab bases
  __shared__ unsigned sebuf[CHUNK2 + 4];            // sorted entries (16 KB) + guard
  __shared__ unsigned char bmap[CHUNK2 + 4];        // bucket id per slot + guard
  const int t = threadIdx.x;
  const int s = blockIdx.x;

  if (s >= NSEG2) {                                 // ---- prep branch ----
    const int bp  = s - NSEG2;                      // 0..31
    const int row = bp * 4 + (t >> 7);              // 0..127
    const int tt  = t & 127;
    const float4* __restrict__ src = (const float4*)(inp + (size_t)row * IN_F);
    #pragma unroll
    for (int j = 0; j < 4; ++j) {
      const int g = 4 * tt + j;                     // 0..511
      const float4 a = src[2 * g];
      const float4 b = src[2 * g + 1];
      uint4 o;
      o.x = f2bf(a.x) | (f2bf(a.y) << 16);
      o.y = f2bf(a.z) | (f2bf(a.w) << 16);
      o.z = f2bf(b.x) | (f2bf(b.y) << 16);
      o.w = f2bf(b.z) | (f2bf(b.w) << 16);
      bg[(size_t)g * BATCH + row] = o;
    }
    return;
  }

  if (t < NBKT) hist[t] = 0u;
  __syncthreads();

  const size_t qb = (size_t)s * (CHUNK2 / 4);
  const int4   ra = ((const int4*)rows)[qb + t];
  const int4   ca = ((const int4*)cols)[qb + t];
  const float4 va = ((const float4*)vals)[qb + t];
  const bool hasB = (t + 512) < (CHUNK2 / 4);       // t < 488
  int4 rb = make_int4(0, 0, 0, 0), cb = rb;
  float4 vb = make_float4(0.f, 0.f, 0.f, 0.f);
  if (hasB) {
    rb = ((const int4*)rows)[qb + 512 + t];
    cb = ((const int4*)cols)[qb + 512 + t];
    vb = ((const float4*)vals)[qb + 512 + t];
  }

  atomicAdd(&hist[(unsigned)ra.x >> 4], 1u); atomicAdd(&hist[(unsigned)ra.y >> 4], 1u);
  atomicAdd(&hist[(unsigned)ra.z >> 4], 1u); atomicAdd(&hist[(unsigned)ra.w >> 4], 1u);
  if (hasB) {
    atomicAdd(&hist[(unsigned)rb.x >> 4], 1u); atomicAdd(&hist[(unsigned)rb.y >> 4], 1u);
    atomicAdd(&hist[(unsigned)rb.z >> 4], 1u); atomicAdd(&hist[(unsigned)rb.w >> 4], 1u);
  }
  __syncthreads();

  // 1-wave exclusive scan over 256 bins (R0's verified pattern, 4 bins/lane)
  if (t < 64) {
    const int lane = t;
    const unsigned c0 = hist[4 * lane], c1 = hist[4 * lane + 1];
    const unsigned c2 = hist[4 * lane + 2], c3 = hist[4 * lane + 3];
    const unsigned tsum = c0 + c1 + c2 + c3;
    unsigned incl = tsum;
    #pragma unroll
    for (int d = 1; d < 64; d <<= 1) {
      const unsigned u = __shfl_up(incl, d, 64);
      if (lane >= d) incl += u;
    }
    const unsigned base = incl - tsum;
    lorig[4 * lane]     = base;
    lorig[4 * lane + 1] = base + c0;
    lorig[4 * lane + 2] = base + c0 + c1;
    lorig[4 * lane + 3] = base + c0 + c1 + c2;
    lcur[4 * lane]      = base;
    lcur[4 * lane + 1]  = base + c0;
    lcur[4 * lane + 2]  = base + c0 + c1;
    lcur[4 * lane + 3]  = base + c0 + c1 + c2;
  }
  __syncthreads();
  if (t < NBKT) gbase[t] = atomicAdd(&gcnt[t], hist[t]);
  __syncthreads();

  #define SCAT(R, C, V) {                                              \
    const unsigned bb = (unsigned)(R) >> 4;                            \
    const unsigned p  = atomicAdd(&lcur[bb], 1u);                      \
    sebuf[p] = (f2bf(V) << 16) | ((unsigned)(C) << 4) | ((unsigned)(R) & 15u); \
    bmap[p]  = (unsigned char)bb; }
  SCAT(ra.x, ca.x, va.x) SCAT(ra.y, ca.y, va.y)
  SCAT(ra.z, ca.z, va.z) SCAT(ra.w, ca.w, va.w)
  if (hasB) {
    SCAT(rb.x, cb.x, vb.x) SCAT(rb.y, cb.y, vb.y)
    SCAT(rb.z, cb.z, vb.z) SCAT(rb.w, cb.w, vb.w)
  }
  #undef SCAT
  __syncthreads();

  // coalesced flush: consecutive w -> (mostly) same bucket -> consecutive dst
  for (int w = t; w < CHUNK2; w += 512) {
    const unsigned e   = sebuf[w];
    const unsigned b   = bmap[w];
    const unsigned pos = gbase[b] + ((unsigned)w - lorig[b]);
    if (pos < (unsigned)BCAP) gbuf[(size_t)b * BCAP + pos] = e;
  }
}

// ---------- K2: FUSED densify(LDS bf16 image) + GEMM -> out (R7 verified) ----------
// Phase A reads entries as uint4 (4 entries/load). Rest verbatim from R7.
__global__ __launch_bounds__(512) void k_fuse(const unsigned* __restrict__ gbuf,
                                              const unsigned* __restrict__ gcnt,
                                              const uint4* __restrict__ bg,
                                              const float* __restrict__ bias,
                                              float* __restrict__ out) {
  __shared__ __align__(16) char smem[131072];       // 128 KB: image, then red alias
  unsigned short* __restrict__ img = (unsigned short*)smem;
  const int t   = threadIdx.x;
  const int bkt = blockIdx.x;                       // 0..255
  const int rt  = bkt * 16;

  {
    uint4* img4 = (uint4*)smem;
    const uint4 z = make_uint4(0u, 0u, 0u, 0u);
    #pragma unroll
    for (int j = 0; j < 16; ++j) img4[j * 512 + t] = z;
  }
  unsigned n = gcnt[bkt];
  if (n > (unsigned)BCAP) n = BCAP;
  __syncthreads();

  const uint4* __restrict__ src4 = (const uint4*)(gbuf + (size_t)bkt * BCAP);
  const unsigned ng = (n + 3u) >> 2;
  #define PROC(E, OK) if (OK) {                                         \
    const unsigned e = (E);                                             \
    const unsigned c = (e >> 4) & 0xfffu;                               \
    const unsigned byte = (c >> 3) * 256u + (e & 15u) * 16u + ((c & 7u) >> 1) * 4u; \
    const unsigned data = (c & 1u) ? (e & 0xffff0000u) : (e >> 16);     \
    const unsigned addr = (unsigned)(uintptr_t)&smem[byte];             \
    asm volatile("ds_pk_add_bf16 %0, %1" :: "v"(addr), "v"(data) : "memory"); }
  for (unsigned i = t; i < ng; i += 512) {
    const uint4 e4 = src4[i];
    const unsigned b4 = 4u * i;
    PROC(e4.x, true)
    PROC(e4.y, b4 + 1 < n)
    PROC(e4.z, b4 + 2 < n)
    PROC(e4.w, b4 + 3 < n)
  }
  #undef PROC
  __syncthreads();

  // ---- Phase B: GEMM for these 16 rows (fragment math verbatim, verified) ----
  const int lane = t & 63;
  const int wid  = t >> 6;                          // 0..7 = K chunk
  const int l15  = lane & 15;
  const int lk   = lane >> 4;                       // 0..3

  f32x4_t acc[8];
  #pragma unroll
  for (int i = 0; i < 8; ++i) { acc[i][0] = 0.f; acc[i][1] = 0.f; acc[i][2] = 0.f; acc[i][3] = 0.f; }

  const int g0 = wid * 64 + lk;
  for (int s = 0; s < 16; ++s) {
    const int g = g0 + s * 4;
    const s16x8_t av = *(const s16x8_t*)&img[((size_t)g * 16 + l15) * 8];
    #pragma unroll
    for (int nf = 0; nf < 8; ++nf) {
      const s16x8_t bv = *(const s16x8_t*)&bg[(size_t)g * BATCH + nf * 16 + l15];
      acc[nf] = __builtin_amdgcn_mfma_f32_16x16x32_bf16(av, bv, acc[nf], 0, 0, 0);
    }
  }
  __syncthreads();                                  // image dead; safe to alias red

  float (*red)[BATCH][20] = (float (*)[BATCH][20])smem;   // 80 KB
  #pragma unroll
  for (int nf = 0; nf < 8; ++nf)
    *(f32x4_t*)&red[wid][nf * 16 + l15][lk * 4] = acc[nf];
  __syncthreads();

  const int b   = t >> 2;                           // 0..127
  const int rr0 = (t & 3) * 4;                      // 0,4,8,12
  float4 sum = *(const float4*)&bias[rt + rr0];
  #pragma unroll
  for (int w = 0; w < 8; ++w) {
    const float4 p = *(const float4*)&red[w][b][rr0];
    sum.x += p.x; sum.y += p.y; sum.z += p.z; sum.w += p.w;
  }
  *(float4*)&out[(size_t)b * OUT_F + rt + rr0] = sum;
}

// ---------- fallback (tiny workspace): correct but slow ----------
__global__ __launch_bounds__(256) void k_init_out(const float* __restrict__ bias,
                                                  float* __restrict__ out) {
  const int i = blockIdx.x * 256 + threadIdx.x;
  out[i] = bias[i & (OUT_F - 1)];
}
__global__ __launch_bounds__(256) void k_atomic(const float* __restrict__ vals,
                                                const int* __restrict__ rows,
                                                const int* __restrict__ cols,
                                                const float* __restrict__ inp,
                                                float* __restrict__ out) {
  const int i = blockIdx.x * 256 + threadIdx.x;
  if (i >= NNZ) return;
  const float v = vals[i];
  const int   r = rows[i];
  const int   c = cols[i];
  for (int b = 0; b < BATCH; ++b)
    atomicAdd(&out[(size_t)b * OUT_F + r], v * inp[(size_t)b * IN_F + c]);
}

extern "C" void kernel_launch(void* const* d_in, const int* in_sizes, int n_in,
                              void* d_out, int out_size, void* d_ws, size_t ws_size,
                              hipStream_t stream) {
  const float* inp      = (const float*)d_in[0];
  const float* w_values = (const float*)d_in[1];
  const int*   w_rows   = (const int*)d_in[2];
  const int*   w_cols   = (const int*)d_in[3];
  const float* bias     = (const float*)d_in[4];
  float*       out      = (float*)d_out;

  const size_t ibf_bytes = (size_t)NGRAN * BATCH * 16;      // 1 MB granule-major B
  const size_t gbuf_bytes= (size_t)NBKT * BCAP * 4;         // 8 MB bucketed entries
  const size_t gcnt_bytes= (size_t)NBKT * 4;                // 1 KB cursors
  const size_t need = ibf_bytes + gbuf_bytes + gcnt_bytes + 64;

  if (ws_size >= need) {
    char* ws = (char*)d_ws;
    uint4*    bg   = (uint4*)ws;     ws += ibf_bytes;
    unsigned* gbuf = (unsigned*)ws;  ws += gbuf_bytes;
    unsigned* gcnt = (unsigned*)ws;

    hipMemsetAsync(gcnt, 0, gcnt_bytes, stream);
    k_bucket16<<<NSEG2 + 32, 512, 0, stream>>>(w_values, w_rows, w_cols, inp,
                                               gcnt, gbuf, bg);
    k_fuse<<<NBKT, 512, 0, stream>>>(gbuf, gcnt, bg, bias, out);
  } else {
    k_init_out<<<(BATCH * OUT_F) / 256, 256, 0, stream>>>(bias, out);
    k_atomic<<<(NNZ + 255) / 256, 256, 0, stream>>>(w_values, w_rows, w_cols, inp, out);
  }
}

// Round 11
// 107.990 us; speedup vs baseline: 1.1264x; 1.0091x over previous
//
#include <hip/hip_runtime.h>
#include <stdint.h>

#define IN_F     4096
#define OUT_F    4096
#define BATCH    128
#define NNZ      1600000
#define NSEG2    400       // scatter blocks; block s owns entries [s*4000, +4000)
#define CHUNK2   4000      // NNZ / NSEG2 exactly (1000 int4 quads)
#define NBKT     256       // row buckets of 16 rows (OUT_F/16)
#define BCAP     8192      // per-bucket entry capacity (mean 6250, +25 sigma)
#define NGRAN    (IN_F / 8)  // 512 k-granules of 8 bf16

typedef float f32x4_t __attribute__((ext_vector_type(4)));
typedef short s16x8_t __attribute__((ext_vector_type(8)));

// fp32 -> bf16 bits (RNE)
__device__ __forceinline__ unsigned f2bf(float f) {
  unsigned u = __float_as_uint(f);
  return (u + 0x7fffu + ((u >> 16) & 1u)) >> 16;
}

// ---------- K1: bucket kernel with in-LDS 256-bin counting sort (R9 verified) ------
// Blocks [0,NSEG2): hist -> 1-wave scan -> LDS scatter (sorted by bucket) ->
// COALESCED flush of per-bucket runs into globally-reserved slabs (one
// atomicAdd per (block,bucket)). Entries packed val16|col12|row4.
// Blocks [NSEG2,+32): inp -> granule-major bf16 bg[g][row].
__global__ __launch_bounds__(512) void k_bucket16(const float* __restrict__ vals,
                                                  const int* __restrict__ rows,
                                                  const int* __restrict__ cols,
                                                  const float* __restrict__ inp,
                                                  unsigned* __restrict__ gcnt,
                                                  unsigned* __restrict__ gbuf,
                                                  uint4* __restrict__ bg) {
  __shared__ unsigned hist[NBKT];                   // counts
  __shared__ unsigned lcur[NBKT];                   // local scatter cursors
  __shared__ unsigned lorig[NBKT];                  // local exclusive bases
  __shared__ unsigned gbase[NBKT];                  // global slab bases
  __shared__ unsigned sebuf[CHUNK2 + 4];            // sorted entries (16 KB) + guard
  __shared__ unsigned char bmap[CHUNK2 + 4];        // bucket id per slot + guard
  const int t = threadIdx.x;
  const int s = blockIdx.x;

  if (s >= NSEG2) {                                 // ---- prep branch ----
    const int bp  = s - NSEG2;                      // 0..31
    const int row = bp * 4 + (t >> 7);              // 0..127
    const int tt  = t & 127;
    const float4* __restrict__ src = (const float4*)(inp + (size_t)row * IN_F);
    #pragma unroll
    for (int j = 0; j < 4; ++j) {
      const int g = 4 * tt + j;                     // 0..511
      const float4 a = src[2 * g];
      const float4 b = src[2 * g + 1];
      uint4 o;
      o.x = f2bf(a.x) | (f2bf(a.y) << 16);
      o.y = f2bf(a.z) | (f2bf(a.w) << 16);
      o.z = f2bf(b.x) | (f2bf(b.y) << 16);
      o.w = f2bf(b.z) | (f2bf(b.w) << 16);
      bg[(size_t)g * BATCH + row] = o;
    }
    return;
  }

  if (t < NBKT) hist[t] = 0u;
  __syncthreads();

  const size_t qb = (size_t)s * (CHUNK2 / 4);
  const int4   ra = ((const int4*)rows)[qb + t];
  const int4   ca = ((const int4*)cols)[qb + t];
  const float4 va = ((const float4*)vals)[qb + t];
  const bool hasB = (t + 512) < (CHUNK2 / 4);       // t < 488
  int4 rb = make_int4(0, 0, 0, 0), cb = rb;
  float4 vb = make_float4(0.f, 0.f, 0.f, 0.f);
  if (hasB) {
    rb = ((const int4*)rows)[qb + 512 + t];
    cb = ((const int4*)cols)[qb + 512 + t];
    vb = ((const float4*)vals)[qb + 512 + t];
  }

  atomicAdd(&hist[(unsigned)ra.x >> 4], 1u); atomicAdd(&hist[(unsigned)ra.y >> 4], 1u);
  atomicAdd(&hist[(unsigned)ra.z >> 4], 1u); atomicAdd(&hist[(unsigned)ra.w >> 4], 1u);
  if (hasB) {
    atomicAdd(&hist[(unsigned)rb.x >> 4], 1u); atomicAdd(&hist[(unsigned)rb.y >> 4], 1u);
    atomicAdd(&hist[(unsigned)rb.z >> 4], 1u); atomicAdd(&hist[(unsigned)rb.w >> 4], 1u);
  }
  __syncthreads();

  // 1-wave exclusive scan over 256 bins (R0's verified pattern, 4 bins/lane)
  if (t < 64) {
    const int lane = t;
    const unsigned c0 = hist[4 * lane], c1 = hist[4 * lane + 1];
    const unsigned c2 = hist[4 * lane + 2], c3 = hist[4 * lane + 3];
    const unsigned tsum = c0 + c1 + c2 + c3;
    unsigned incl = tsum;
    #pragma unroll
    for (int d = 1; d < 64; d <<= 1) {
      const unsigned u = __shfl_up(incl, d, 64);
      if (lane >= d) incl += u;
    }
    const unsigned base = incl - tsum;
    lorig[4 * lane]     = base;
    lorig[4 * lane + 1] = base + c0;
    lorig[4 * lane + 2] = base + c0 + c1;
    lorig[4 * lane + 3] = base + c0 + c1 + c2;
    lcur[4 * lane]      = base;
    lcur[4 * lane + 1]  = base + c0;
    lcur[4 * lane + 2]  = base + c0 + c1;
    lcur[4 * lane + 3]  = base + c0 + c1 + c2;
  }
  __syncthreads();
  if (t < NBKT) gbase[t] = atomicAdd(&gcnt[t], hist[t]);
  __syncthreads();

  #define SCAT(R, C, V) {                                              \
    const unsigned bb = (unsigned)(R) >> 4;                            \
    const unsigned p  = atomicAdd(&lcur[bb], 1u);                      \
    sebuf[p] = (f2bf(V) << 16) | ((unsigned)(C) << 4) | ((unsigned)(R) & 15u); \
    bmap[p]  = (unsigned char)bb; }
  SCAT(ra.x, ca.x, va.x) SCAT(ra.y, ca.y, va.y)
  SCAT(ra.z, ca.z, va.z) SCAT(ra.w, ca.w, va.w)
  if (hasB) {
    SCAT(rb.x, cb.x, vb.x) SCAT(rb.y, cb.y, vb.y)
    SCAT(rb.z, cb.z, vb.z) SCAT(rb.w, cb.w, vb.w)
  }
  #undef SCAT
  __syncthreads();

  // coalesced flush: consecutive w -> (mostly) same bucket -> consecutive dst
  for (int w = t; w < CHUNK2; w += 512) {
    const unsigned e   = sebuf[w];
    const unsigned b   = bmap[w];
    const unsigned pos = gbase[b] + ((unsigned)w - lorig[b]);
    if (pos < (unsigned)BCAP) gbuf[(size_t)b * BCAP + pos] = e;
  }
}

// ---------- K2: FUSED densify(LDS bf16 image) + GEMM -> out (R9 verified) ----------
__global__ __launch_bounds__(512) void k_fuse(const unsigned* __restrict__ gbuf,
                                              const unsigned* __restrict__ gcnt,
                                              const uint4* __restrict__ bg,
                                              const float* __restrict__ bias,
                                              float* __restrict__ out) {
  __shared__ __align__(16) char smem[131072];       // 128 KB: image, then red alias
  unsigned short* __restrict__ img = (unsigned short*)smem;
  const int t   = threadIdx.x;
  const int bkt = blockIdx.x;                       // 0..255
  const int rt  = bkt * 16;

  {
    uint4* img4 = (uint4*)smem;
    const uint4 z = make_uint4(0u, 0u, 0u, 0u);
    #pragma unroll
    for (int j = 0; j < 16; ++j) img4[j * 512 + t] = z;
  }
  unsigned n = gcnt[bkt];
  if (n > (unsigned)BCAP) n = BCAP;
  __syncthreads();

  const uint4* __restrict__ src4 = (const uint4*)(gbuf + (size_t)bkt * BCAP);
  const unsigned ng = (n + 3u) >> 2;
  #define PROC(E, OK) if (OK) {                                         \
    const unsigned e = (E);                                             \
    const unsigned c = (e >> 4) & 0xfffu;                               \
    const unsigned byte = (c >> 3) * 256u + (e & 15u) * 16u + ((c & 7u) >> 1) * 4u; \
    const unsigned data = (c & 1u) ? (e & 0xffff0000u) : (e >> 16);     \
    const unsigned addr = (unsigned)(uintptr_t)&smem[byte];             \
    asm volatile("ds_pk_add_bf16 %0, %1" :: "v"(addr), "v"(data) : "memory"); }
  for (unsigned i = t; i < ng; i += 512) {
    const uint4 e4 = src4[i];
    const unsigned b4 = 4u * i;
    PROC(e4.x, true)
    PROC(e4.y, b4 + 1 < n)
    PROC(e4.z, b4 + 2 < n)
    PROC(e4.w, b4 + 3 < n)
  }
  #undef PROC
  __syncthreads();

  // ---- Phase B: GEMM for these 16 rows (fragment math verbatim, verified) ----
  const int lane = t & 63;
  const int wid  = t >> 6;                          // 0..7 = K chunk
  const int l15  = lane & 15;
  const int lk   = lane >> 4;                       // 0..3

  f32x4_t acc[8];
  #pragma unroll
  for (int i = 0; i < 8; ++i) { acc[i][0] = 0.f; acc[i][1] = 0.f; acc[i][2] = 0.f; acc[i][3] = 0.f; }

  const int g0 = wid * 64 + lk;
  for (int s = 0; s < 16; ++s) {
    const int g = g0 + s * 4;
    const s16x8_t av = *(const s16x8_t*)&img[((size_t)g * 16 + l15) * 8];
    #pragma unroll
    for (int nf = 0; nf < 8; ++nf) {
      const s16x8_t bv = *(const s16x8_t*)&bg[(size_t)g * BATCH + nf * 16 + l15];
      acc[nf] = __builtin_amdgcn_mfma_f32_16x16x32_bf16(av, bv, acc[nf], 0, 0, 0);
    }
  }
  __syncthreads();                                  // image dead; safe to alias red

  float (*red)[BATCH][20] = (float (*)[BATCH][20])smem;   // 80 KB
  #pragma unroll
  for (int nf = 0; nf < 8; ++nf)
    *(f32x4_t*)&red[wid][nf * 16 + l15][lk * 4] = acc[nf];
  __syncthreads();

  const int b   = t >> 2;                           // 0..127
  const int rr0 = (t & 3) * 4;                      // 0,4,8,12
  float4 sum = *(const float4*)&bias[rt + rr0];
  #pragma unroll
  for (int w = 0; w < 8; ++w) {
    const float4 p = *(const float4*)&red[w][b][rr0];
    sum.x += p.x; sum.y += p.y; sum.z += p.z; sum.w += p.w;
  }
  *(float4*)&out[(size_t)b * OUT_F + rt + rr0] = sum;
}

// ---------- fallback (tiny workspace): correct but slow ----------
__global__ __launch_bounds__(256) void k_init_out(const float* __restrict__ bias,
                                                  float* __restrict__ out) {
  const int i = blockIdx.x * 256 + threadIdx.x;
  out[i] = bias[i & (OUT_F - 1)];
}
__global__ __launch_bounds__(256) void k_atomic(const float* __restrict__ vals,
                                                const int* __restrict__ rows,
                                                const int* __restrict__ cols,
                                                const float* __restrict__ inp,
                                                float* __restrict__ out) {
  const int i = blockIdx.x * 256 + threadIdx.x;
  if (i >= NNZ) return;
  const float v = vals[i];
  const int   r = rows[i];
  const int   c = cols[i];
  for (int b = 0; b < BATCH; ++b)
    atomicAdd(&out[(size_t)b * OUT_F + r], v * inp[(size_t)b * IN_F + c]);
}

extern "C" void kernel_launch(void* const* d_in, const int* in_sizes, int n_in,
                              void* d_out, int out_size, void* d_ws, size_t ws_size,
                              hipStream_t stream) {
  const float* inp      = (const float*)d_in[0];
  const float* w_values = (const float*)d_in[1];
  const int*   w_rows   = (const int*)d_in[2];
  const int*   w_cols   = (const int*)d_in[3];
  const float* bias     = (const float*)d_in[4];
  float*       out      = (float*)d_out;

  const size_t ibf_bytes = (size_t)NGRAN * BATCH * 16;      // 1 MB granule-major B
  const size_t gbuf_bytes= (size_t)NBKT * BCAP * 4;         // 8 MB bucketed entries
  const size_t gcnt_bytes= (size_t)NBKT * 4;                // 1 KB cursors
  const size_t need = ibf_bytes + gbuf_bytes + gcnt_bytes + 64;

  if (ws_size >= need) {
    char* ws = (char*)d_ws;
    uint4*    bg   = (uint4*)ws;     ws += ibf_bytes;
    unsigned* gbuf = (unsigned*)ws;  ws += gbuf_bytes;
    unsigned* gcnt = (unsigned*)ws;

    hipMemsetAsync(gcnt, 0, gcnt_bytes, stream);
    k_bucket16<<<NSEG2 + 32, 512, 0, stream>>>(w_values, w_rows, w_cols, inp,
                                               gcnt, gbuf, bg);
    k_fuse<<<NBKT, 512, 0, stream>>>(gbuf, gcnt, bg, bias, out);
  } else {
    k_init_out<<<(BATCH * OUT_F) / 256, 256, 0, stream>>>(bias, out);
    k_atomic<<<(NNZ + 255) / 256, 256, 0, stream>>>(w_values, w_rows, w_cols, inp, out);
  }
}